// Round 1
// baseline (656.697 us; speedup 1.0000x reference)
//
#include <hip/hip_runtime.h>
#include <math.h>

#define SEQ    100
#define BATCH  2048
#define DIM    128
#define NF     51        // rfft bins = SEQ/2+1
#define KPAD   52        // padded k for even split
#define NLAYER 2
#define MTOT   (BATCH * NF)   // 104448 values for the quantile

// ---------------------------------------------------------------- tables ---
// tblF: [n][KPAD] float2 = (cos(2*pi*k*n/100)/10, -sin(...)/10), k==51 -> 0
// tblI: [k][SEQ]  float2 = (a_k*cos(2*pi*k*n/100), -a_k*sin(...)),
//       a_k = 0.1 for k=0,50 ; 0.2 otherwise (c2r with ortho norm)
__global__ void k_tables(float* __restrict__ tblF, float* __restrict__ tblI) {
    const int i = blockIdx.x * 256 + threadIdx.x;
    const float W = 6.28318530717958647692f / (float)SEQ;
    if (i < SEQ * KPAD) {
        const int n = i / KPAD, k = i - n * KPAD;
        float cr = 0.f, ci = 0.f;
        if (k < NF) {
            const int m = (k * n) % SEQ;
            float s, c;
            sincosf((float)m * W, &s, &c);
            cr = 0.1f * c; ci = -0.1f * s;
        }
        tblF[2*i] = cr; tblF[2*i+1] = ci;
    }
    if (i < NF * SEQ) {
        const int k = i / SEQ, n = i - k * SEQ;
        const int m = (k * n) % SEQ;
        float s, c;
        sincosf((float)m * W, &s, &c);
        const float ak = (k == 0 || k == 50) ? 0.1f : 0.2f;
        tblI[2*i] = ak * c; tblI[2*i+1] = -ak * s;
    }
}

// ------------------------------------------------- LN + rfft + energy ------
// One block per batch b. LN into LDS, direct DFT along n, energy + lower
// median + norm_e fused.
__global__ __launch_bounds__(256, 2) void k_ln_rfft(
    const float* __restrict__ x,      // [SEQ][BATCH][DIM]
    const float* __restrict__ gamma,  // [DIM] (layer slice)
    const float* __restrict__ beta,   // [DIM]
    const float* __restrict__ tblF,   // [SEQ][KPAD] float2
    float* __restrict__ Xout,         // [BATCH][NF][DIM] float2
    float* __restrict__ normE)        // [BATCH][NF]
{
    __shared__ float h[SEQ][DIM];     // 51.2 KB
    __shared__ float epart[KPAD][4];
    __shared__ float energy[NF];
    __shared__ float median_s;

    const int b    = blockIdx.x;
    const int tid  = threadIdx.x;
    const int lane = tid & 63;
    const int wave = tid >> 6;

    // ---- LayerNorm: wave w handles rows n = w, w+4, ... ; 2 ch per lane
    {
        const int c0 = lane * 2;
        const float g0 = gamma[c0], g1 = gamma[c0 + 1];
        const float be0 = beta[c0], be1 = beta[c0 + 1];
        for (int n = wave; n < SEQ; n += 4) {
            const float2 v = *reinterpret_cast<const float2*>(
                &x[(size_t)n * (BATCH * DIM) + (size_t)b * DIM + c0]);
            float s  = v.x + v.y;
            float s2 = fmaf(v.x, v.x, v.y * v.y);
            #pragma unroll
            for (int off = 32; off > 0; off >>= 1) {
                s  += __shfl_xor(s,  off, 64);
                s2 += __shfl_xor(s2, off, 64);
            }
            const float mu   = s * (1.0f / DIM);
            const float var  = s2 * (1.0f / DIM) - mu * mu;
            const float rstd = rsqrtf(var + 1e-5f);
            float2 hv;
            hv.x = fmaf((v.x - mu) * rstd, g0, be0);
            hv.y = fmaf((v.y - mu) * rstd, g1, be1);
            *reinterpret_cast<float2*>(&h[n][c0]) = hv;
        }
    }
    __syncthreads();

    // ---- DFT: thread = (kk, c); k = kk*26 + j, j = 0..25
    const int c  = tid & 127;
    const int kk = __builtin_amdgcn_readfirstlane(tid >> 7);  // wave-uniform
    float accR[26], accI[26];
    #pragma unroll
    for (int j = 0; j < 26; ++j) { accR[j] = 0.f; accI[j] = 0.f; }

    const float2* __restrict__ tF = reinterpret_cast<const float2*>(tblF);
    for (int n = 0; n < SEQ; ++n) {
        const float hv = h[n][c];
        const float2* t = tF + n * KPAD + kk * 26;   // uniform addr -> s_load
        #pragma unroll
        for (int j = 0; j < 26; ++j) {
            const float2 cs = t[j];
            accR[j] = fmaf(hv, cs.x, accR[j]);
            accI[j] = fmaf(hv, cs.y, accI[j]);
        }
    }

    // ---- store X + per-k energy partials (sum |X|^2 over c)
    float2* __restrict__ Xf2 = reinterpret_cast<float2*>(Xout);
    #pragma unroll
    for (int j = 0; j < 26; ++j) {
        const int k = kk * 26 + j;
        float e = fmaf(accR[j], accR[j], accI[j] * accI[j]);
        #pragma unroll
        for (int off = 32; off > 0; off >>= 1) e += __shfl_xor(e, off, 64);
        if (lane == 0) epart[k][wave] = e;
        if (k < NF)
            Xf2[((size_t)b * NF + k) * DIM + c] = make_float2(accR[j], accI[j]);
    }
    __syncthreads();

    if (tid < NF) {
        const int w0 = (tid < 26) ? 0 : 2;
        energy[tid] = epart[tid][w0] + epart[tid][w0 + 1];
    }
    __syncthreads();
    // lower median: rank (NF-1)/2 = 25 with index tie-break
    if (tid < NF) {
        const float e = energy[tid];
        int cnt = 0;
        for (int j = 0; j < NF; ++j) {
            const float ej = energy[j];
            cnt += (ej < e || (ej == e && j < tid)) ? 1 : 0;
        }
        if (cnt == (NF - 1) / 2) median_s = e;
    }
    __syncthreads();
    if (tid < NF) normE[b * NF + tid] = energy[tid] / (median_s + 1e-6f);
}

// ----------------------------------------------------- radix select --------
// Exact k-th / (k+1)-th smallest of MTOT non-negative floats via 3 rounds
// of bit-histogramming (11/11/10 bits). sel layout (u32):
//   [0]=prefix0 [1]=cnt_below0 [2]=prefix1 [3]=cnt_below1 [4]=v0bits [5]=v1bits
__global__ void k_hist(const float* __restrict__ normE,
                       unsigned* __restrict__ hist,
                       const unsigned* __restrict__ sel,
                       const int round)
{
    __shared__ unsigned lh[4096];
    const int bins  = (round == 2) ? 1024 : 2048;
    const int shift = (round == 0) ? 21 : (round == 1) ? 10 : 0;
    for (int i = threadIdx.x; i < 2 * bins; i += blockDim.x) lh[i] = 0;
    __syncthreads();
    unsigned p0 = 0, p1 = 0, himask = 0;
    if (round > 0) {
        p0 = sel[0]; p1 = sel[2];
        himask = (round == 1) ? 0xFFE00000u : 0xFFFFFC00u;
    }
    for (int i = blockIdx.x * blockDim.x + threadIdx.x; i < MTOT;
         i += gridDim.x * blockDim.x) {
        const unsigned v = __float_as_uint(normE[i]);
        if (round == 0) {
            atomicAdd(&lh[v >> 21], 1u);
        } else {
            const unsigned bin = (v >> shift) & (unsigned)(bins - 1);
            if ((v & himask) == p0) atomicAdd(&lh[bin], 1u);
            if ((v & himask) == p1) atomicAdd(&lh[bins + bin], 1u);
        }
    }
    __syncthreads();
    for (int i = threadIdx.x; i < 2 * bins; i += blockDim.x) {
        const unsigned cnt = lh[i];
        if (cnt) atomicAdd(&hist[i], cnt);
    }
}

__global__ void k_scan(unsigned* __restrict__ hist,
                       unsigned* __restrict__ sel,
                       const float* __restrict__ thrp,
                       const int layer, const int round,
                       float* __restrict__ out_thresh)
{
    const int j    = threadIdx.x >> 6;   // wave 0 -> rank k, wave 1 -> rank k+1
    const int lane = threadIdx.x & 63;
    const int bins  = (round == 2) ? 1024 : 2048;
    const int shift = (round == 0) ? 21 : (round == 1) ? 10 : 0;
    const float thr  = thrp[layer];
    const float qpos = thr * (float)(MTOT - 1);
    const float lo   = floorf(qpos);
    const unsigned r = (unsigned)lo + (unsigned)j;
    unsigned prefix = 0, cbelow = 0;
    if (round > 0) { prefix = sel[2 * j]; cbelow = sel[2 * j + 1]; }
    const unsigned rem = r - cbelow;
    const unsigned* H = hist + ((round == 0) ? 0 : j * bins);
    const int per  = bins / 64;
    const int base = lane * per;
    unsigned sum = 0;
    for (int i = 0; i < per; ++i) sum += H[base + i];
    unsigned pre = sum;
    #pragma unroll
    for (int off = 1; off < 64; off <<= 1) {
        const unsigned t = __shfl_up(pre, off, 64);
        if (lane >= off) pre += t;
    }
    const unsigned excl = pre - sum;  // count before this lane's chunk
    if (rem >= excl && rem < excl + sum) {
        unsigned cum = excl;
        unsigned t = base;
        for (int i = 0; i < per; ++i) {
            const unsigned hc = H[base + i];
            if (rem < cum + hc) { t = (unsigned)(base + i); break; }
            cum += hc;
        }
        sel[2 * j]     = prefix | (t << shift);
        sel[2 * j + 1] = cbelow + cum;
        if (round == 2) sel[4 + j] = prefix | t;   // exact value bits
    }
    __syncthreads();
    for (int i = threadIdx.x; i < 4096; i += blockDim.x) hist[i] = 0;
    if (round == 2) {
        __syncthreads();
        if (threadIdx.x == 0) {
            const float v0 = __uint_as_float(sel[4]);
            const float v1 = __uint_as_float(sel[5]);
            const float frac = qpos - lo;
            out_thresh[0] = v0 * (1.0f - frac) + v1 * frac;  // linear interp
        }
    }
}

// ------------------------------------- mask + weight + irfft + residual ----
__global__ __launch_bounds__(256, 2) void k_irfft(
    const float* __restrict__ xin,    // [SEQ][BATCH][DIM]
    const float* __restrict__ Xin,    // [BATCH][NF][DIM] float2
    const float* __restrict__ normE,  // [BATCH][NF]
    const float* __restrict__ cw,     // [DIM][2] (layer slice)
    const float* __restrict__ cwh,    // [DIM][2]
    const float* __restrict__ tblI,   // [NF][SEQ] float2
    const float* __restrict__ thresh, // scalar
    float* __restrict__ xout)         // [SEQ][BATCH][DIM]
{
    __shared__ float2 Xw[NF][DIM];    // 52.2 KB
    __shared__ float mask_s[NF];

    const int b   = blockIdx.x;
    const int tid = threadIdx.x;

    if (tid < NF)
        mask_s[tid] = (normE[b * NF + tid] < thresh[0]) ? 1.0f : 0.0f;
    __syncthreads();

    // load X, apply (w + mask*wh) complex factor
    const float2* __restrict__ Xg =
        reinterpret_cast<const float2*>(Xin) + (size_t)b * NF * DIM;
    for (int e = tid; e < NF * DIM; e += 256) {
        const int k = e >> 7, cc = e & 127;
        const float2 xf = Xg[e];
        const float m = mask_s[k];
        const float fre = fmaf(m, cwh[2 * cc],     cw[2 * cc]);
        const float fim = fmaf(m, cwh[2 * cc + 1], cw[2 * cc + 1]);
        Xw[k][cc] = make_float2(xf.x * fre - xf.y * fim,
                                xf.x * fim + xf.y * fre);
    }
    __syncthreads();

    // inverse DFT: thread = (nn, c); n = nn*50 + j
    const int c  = tid & 127;
    const int nn = __builtin_amdgcn_readfirstlane(tid >> 7);  // wave-uniform
    float acc[50];
    #pragma unroll
    for (int j = 0; j < 50; ++j) acc[j] = 0.f;

    const float2* __restrict__ tI = reinterpret_cast<const float2*>(tblI);
    for (int k = 0; k < NF; ++k) {
        const float2 xv = Xw[k][c];
        const float2* t = tI + k * SEQ + nn * 50;  // uniform addr -> s_load
        #pragma unroll
        for (int j = 0; j < 50; ++j) {
            const float2 cs = t[j];
            acc[j] = fmaf(xv.x, cs.x, acc[j]);  // Re*a_k*cos
            acc[j] = fmaf(xv.y, cs.y, acc[j]);  // Im*(-a_k*sin)
        }
    }

    for (int j = 0; j < 50; ++j) {
        const int n = nn * 50 + j;
        const size_t idx = (size_t)n * (BATCH * DIM) + (size_t)b * DIM + c;
        xout[idx] = xin[idx] + acc[j];
    }
}

// ---------------------------------------------------------------------------
extern "C" void kernel_launch(void* const* d_in, const int* in_sizes, int n_in,
                              void* d_out, int out_size, void* d_ws, size_t ws_size,
                              hipStream_t stream)
{
    const float* x    = (const float*)d_in[0];
    const float* cw   = (const float*)d_in[1];  // [L][DIM][2]
    const float* cwh  = (const float*)d_in[2];  // [L][DIM][2]
    const float* thrp = (const float*)d_in[3];  // [L]
    const float* gam  = (const float*)d_in[4];  // [L][DIM]
    const float* bet  = (const float*)d_in[5];  // [L][DIM]
    float* out = (float*)d_out;

    char* ws = (char*)d_ws;
    size_t off = 0;
    float* X = (float*)(ws + off);
    off += (size_t)BATCH * NF * DIM * 2 * sizeof(float);      // 106,954,752
    float* normE = (float*)(ws + off);
    off += (size_t)MTOT * sizeof(float);                      // 417,792
    off = (off + 255) & ~(size_t)255;
    float* tblF = (float*)(ws + off);
    off += (size_t)SEQ * KPAD * 2 * sizeof(float);            // 41,600
    off = (off + 255) & ~(size_t)255;
    float* tblI = (float*)(ws + off);
    off += (size_t)NF * SEQ * 2 * sizeof(float);              // 40,800
    off = (off + 255) & ~(size_t)255;
    unsigned* hist = (unsigned*)(ws + off);
    off += 4096 * sizeof(unsigned);
    unsigned* sel = (unsigned*)(ws + off);
    off += 64;
    float* thresh = (float*)(ws + off);

    k_tables<<<21, 256, 0, stream>>>(tblF, tblI);
    hipMemsetAsync(hist, 0, 4096 * sizeof(unsigned), stream);

    for (int l = 0; l < NLAYER; ++l) {
        const float* xi = (l == 0) ? x : out;
        k_ln_rfft<<<BATCH, 256, 0, stream>>>(
            xi, gam + l * DIM, bet + l * DIM, tblF, X, normE);
        for (int r = 0; r < 3; ++r) {
            k_hist<<<96, 256, 0, stream>>>(normE, hist, sel, r);
            k_scan<<<1, 128, 0, stream>>>(hist, sel, thrp, l, r, thresh);
        }
        k_irfft<<<BATCH, 256, 0, stream>>>(
            xi, X, normE, cw + l * DIM * 2, cwh + l * DIM * 2, tblI, thresh, out);
    }
}

// Round 2
// 626.049 us; speedup vs baseline: 1.0490x; 1.0490x over previous
//
#include <hip/hip_runtime.h>
#include <math.h>

#define SEQ    100
#define BATCH  2048
#define DIM    128
#define NF     51
#define NP     128            // padded n (K of fwd, M of inv)
#define KP     64             // padded k (M of fwd, K of inv)
#define NLAYER 2
#define MTOT   (BATCH * NF)
#define BD     (BATCH * DIM)

typedef __attribute__((ext_vector_type(8))) short bf16x8;
typedef __attribute__((ext_vector_type(4))) short bf16x4;
typedef __attribute__((ext_vector_type(4))) float f32x4v;

__device__ __forceinline__ unsigned short f2bf(float f) {
    unsigned u = __float_as_uint(f);
    return (unsigned short)((u + 0x7FFFu + ((u >> 16) & 1u)) >> 16);
}

// ---------------------------------------------------------------- tables ---
// imgF: fwd DFT A-operand image, bf16, swizzled. element (p,k,n):
//   p0 = 0.1*cos(2*pi*k*n/100), p1 = -0.1*sin(...), zero for k>=51 or n>=100
//   flat: (p*KP + k)*NP + ((n>>3)^(k&7))*8 + (n&7)
// imgI: inv DFT A-operand image. element (p,n,k):
//   p0 = a_k*cos, p1 = -a_k*sin, a_k = 0.1*(k==0||k==50?1:2)
//   flat: (p*NP + n)*KP + ((k>>3)^(n&7))*8 + (k&7)
__global__ void k_tables(unsigned short* __restrict__ imgF,
                         unsigned short* __restrict__ imgI) {
    const int i = blockIdx.x * 256 + threadIdx.x;
    const float W = 6.28318530717958647692f / 100.f;
    if (i < 2 * KP * NP) {
        const int p = i >> 13, k = (i >> 7) & 63, n = i & 127;
        float v = 0.f;
        if (k < NF && n < SEQ) {
            float s, c; sincosf((float)((k * n) % 100) * W, &s, &c);
            v = 0.1f * (p ? -s : c);
        }
        imgF[(p * KP + k) * NP + ((((n >> 3) ^ (k & 7)) << 3) | (n & 7))] = f2bf(v);
    }
    if (i < 2 * NP * KP) {
        const int p = i >> 13, n = (i >> 6) & 127, k = i & 63;
        float v = 0.f;
        if (k < NF && n < SEQ) {
            float s, c; sincosf((float)((k * n) % 100) * W, &s, &c);
            const float a = (k == 0 || k == 50) ? 0.1f : 0.2f;
            v = p ? -a * s : a * c;
        }
        imgI[(p * NP + n) * KP + ((((k >> 3) ^ (n & 7)) << 3) | (k & 7))] = f2bf(v);
    }
}

// ------------------------------------------------- A: LN + fwd DFT + normE -
__global__ __launch_bounds__(256, 2) void k_fwd(
    const float* __restrict__ x,
    const float* __restrict__ gamma, const float* __restrict__ beta,
    const unsigned short* __restrict__ imgF,
    float* __restrict__ mustat,        // [BATCH][SEQ] float2 (mu, rstd)
    float* __restrict__ normE)         // [BATCH][NF]
{
    __shared__ __align__(16) unsigned short tbl[2 * KP * NP];  // 32 KB
    __shared__ __align__(16) unsigned short hT[DIM * NP];      // 32 KB
    __shared__ float mu_s[SEQ], rs_s[SEQ];
    __shared__ float energy[KP];
    __shared__ float med_s;

    const int b = blockIdx.x, t = threadIdx.x;
    const int lane = t & 63, wv = t >> 6;
    const int g4 = lane >> 4;

    // phase 0: stage fwd table
    {
        const int4* g = (const int4*)imgF;
        int4* lp = (int4*)tbl;
        #pragma unroll
        for (int j = 0; j < 8; ++j) lp[t + j * 256] = g[t + j * 256];
    }

    // phase 0b: LN stats, wave per n
    {
        const int c0 = lane * 2;
        for (int n = wv; n < SEQ; n += 4) {
            const float2 v = *(const float2*)&x[(size_t)n * BD + (size_t)b * DIM + c0];
            float s = v.x + v.y, s2 = fmaf(v.x, v.x, v.y * v.y);
            #pragma unroll
            for (int off = 32; off > 0; off >>= 1) {
                s += __shfl_xor(s, off, 64); s2 += __shfl_xor(s2, off, 64);
            }
            const float mu = s * (1.f / DIM);
            const float var = s2 * (1.f / DIM) - mu * mu;
            const float rs = rsqrtf(var + 1e-5f);
            if (lane == 0) {
                mu_s[n] = mu; rs_s[n] = rs;
                *(float2*)&mustat[((size_t)b * SEQ + n) * 2] = make_float2(mu, rs);
            }
        }
    }
    __syncthreads();

    // phase 1: h^T into LDS (bf16, swizzled): row c, cols n
    {
        const int c = t & 127, g2 = t >> 7;
        const float ga = gamma[c], be = beta[c];
        for (int ch = g2; ch < 16; ch += 2) {
            bf16x8 v;
            #pragma unroll
            for (int j = 0; j < 8; ++j) {
                const int n = ch * 8 + j;
                float hv = 0.f;
                if (n < SEQ)
                    hv = fmaf((x[(size_t)n * BD + (size_t)b * DIM + c] - mu_s[n]) * rs_s[n], ga, be);
                v[j] = (short)f2bf(hv);
            }
            *(bf16x8*)&hT[c * NP + ((ch ^ (c & 7)) << 3)] = v;
        }
    }
    __syncthreads();

    // phase 2: fwd MFMA. wave wv owns k rows 16wv..16wv+15
    f32x4v aR[8], aI[8];
    #pragma unroll
    for (int i = 0; i < 8; ++i) { aR[i] = (f32x4v){0.f,0.f,0.f,0.f}; aI[i] = (f32x4v){0.f,0.f,0.f,0.f}; }

    const int r = wv * 16 + (lane & 15);
    bf16x8 A0[4], A1[4];
    #pragma unroll
    for (int ks = 0; ks < 4; ++ks) {
        const int ch = ks * 4 + g4;
        const int swz = (ch ^ (r & 7)) << 3;
        A0[ks] = *(const bf16x8*)&tbl[r * NP + swz];
        A1[ks] = *(const bf16x8*)&tbl[(KP + r) * NP + swz];
    }
    #pragma unroll
    for (int ks = 0; ks < 4; ++ks) {
        const int ch = ks * 4 + g4;
        #pragma unroll
        for (int nt = 0; nt < 8; ++nt) {
            const int c = nt * 16 + (lane & 15);
            const bf16x8 B = *(const bf16x8*)&hT[c * NP + ((ch ^ (c & 7)) << 3)];
            aR[nt] = __builtin_amdgcn_mfma_f32_16x16x32_bf16(A0[ks], B, aR[nt], 0, 0, 0);
            aI[nt] = __builtin_amdgcn_mfma_f32_16x16x32_bf16(A1[ks], B, aI[nt], 0, 0, 0);
        }
    }

    // phase 3: energy[k] = sum_c |X|^2 ; acc layout col=lane&15, row=4*g4+reg
    #pragma unroll
    for (int reg = 0; reg < 4; ++reg) {
        float e = 0.f;
        #pragma unroll
        for (int nt = 0; nt < 8; ++nt)
            e += aR[nt][reg] * aR[nt][reg] + aI[nt][reg] * aI[nt][reg];
        e += __shfl_xor(e, 1, 64); e += __shfl_xor(e, 2, 64);
        e += __shfl_xor(e, 4, 64); e += __shfl_xor(e, 8, 64);
        if ((lane & 15) == 0) energy[wv * 16 + g4 * 4 + reg] = e;
    }
    __syncthreads();

    // phase 4: lower median (rank 25 of 51) + normE
    if (t < NF) {
        const float e = energy[t];
        int cnt = 0;
        for (int j = 0; j < NF; ++j) {
            const float ej = energy[j];
            cnt += (ej < e || (ej == e && j < t)) ? 1 : 0;
        }
        if (cnt == (NF - 1) / 2) med_s = e;
    }
    __syncthreads();
    if (t < NF) normE[b * NF + t] = energy[t] / (med_s + 1e-6f);
}

// ----------------------------------------------------- radix select --------
__global__ void k_hist(const float* __restrict__ normE,
                       unsigned* __restrict__ hist,
                       const unsigned* __restrict__ sel,
                       const int round)
{
    __shared__ unsigned lh[4096];
    const int bins  = (round == 2) ? 1024 : 2048;
    const int shift = (round == 0) ? 21 : (round == 1) ? 10 : 0;
    for (int i = threadIdx.x; i < 2 * bins; i += blockDim.x) lh[i] = 0;
    __syncthreads();
    unsigned p0 = 0, p1 = 0, himask = 0;
    if (round > 0) {
        p0 = sel[0]; p1 = sel[2];
        himask = (round == 1) ? 0xFFE00000u : 0xFFFFFC00u;
    }
    for (int i = blockIdx.x * blockDim.x + threadIdx.x; i < MTOT;
         i += gridDim.x * blockDim.x) {
        const unsigned v = __float_as_uint(normE[i]);
        if (round == 0) {
            atomicAdd(&lh[v >> 21], 1u);
        } else {
            const unsigned bin = (v >> shift) & (unsigned)(bins - 1);
            if ((v & himask) == p0) atomicAdd(&lh[bin], 1u);
            if ((v & himask) == p1) atomicAdd(&lh[bins + bin], 1u);
        }
    }
    __syncthreads();
    for (int i = threadIdx.x; i < 2 * bins; i += blockDim.x) {
        const unsigned cnt = lh[i];
        if (cnt) atomicAdd(&hist[i], cnt);
    }
}

__global__ void k_scan(unsigned* __restrict__ hist,
                       unsigned* __restrict__ sel,
                       const float* __restrict__ thrp,
                       const int layer, const int round,
                       float* __restrict__ out_thresh)
{
    const int j    = threadIdx.x >> 6;
    const int lane = threadIdx.x & 63;
    const int bins  = (round == 2) ? 1024 : 2048;
    const int shift = (round == 0) ? 21 : (round == 1) ? 10 : 0;
    const float thr  = thrp[layer];
    const float qpos = thr * (float)(MTOT - 1);
    const float lo   = floorf(qpos);
    const unsigned r = (unsigned)lo + (unsigned)j;
    unsigned prefix = 0, cbelow = 0;
    if (round > 0) { prefix = sel[2 * j]; cbelow = sel[2 * j + 1]; }
    const unsigned rem = r - cbelow;
    const unsigned* H = hist + ((round == 0) ? 0 : j * bins);
    const int per  = bins / 64;
    const int base = lane * per;
    unsigned sum = 0;
    for (int i = 0; i < per; ++i) sum += H[base + i];
    unsigned pre = sum;
    #pragma unroll
    for (int off = 1; off < 64; off <<= 1) {
        const unsigned tt = __shfl_up(pre, off, 64);
        if (lane >= off) pre += tt;
    }
    const unsigned excl = pre - sum;
    if (rem >= excl && rem < excl + sum) {
        unsigned cum = excl;
        unsigned tb = base;
        for (int i = 0; i < per; ++i) {
            const unsigned hc = H[base + i];
            if (rem < cum + hc) { tb = (unsigned)(base + i); break; }
            cum += hc;
        }
        sel[2 * j]     = prefix | (tb << shift);
        sel[2 * j + 1] = cbelow + cum;
        if (round == 2) sel[4 + j] = prefix | tb;
    }
    __syncthreads();
    for (int i = threadIdx.x; i < 4096; i += blockDim.x) hist[i] = 0;
    if (round == 2) {
        __syncthreads();
        if (threadIdx.x == 0) {
            const float v0 = __uint_as_float(sel[4]);
            const float v1 = __uint_as_float(sel[5]);
            const float frac = qpos - lo;
            out_thresh[0] = v0 * (1.0f - frac) + v1 * frac;
        }
    }
}

// --------------------- C: LN + fwd DFT + weights + inv DFT + residual ------
__global__ __launch_bounds__(256, 2) void k_asb(
    const float* __restrict__ x,
    const float* __restrict__ gamma, const float* __restrict__ beta,
    const float* __restrict__ cw, const float* __restrict__ cwh,
    const unsigned short* __restrict__ imgF, const unsigned short* __restrict__ imgI,
    const float* __restrict__ mustat, const float* __restrict__ normE,
    const float* __restrict__ thresh,
    float* __restrict__ out)
{
    __shared__ __align__(16) unsigned short tbl[2 * KP * NP];  // fwd then inv table
    __shared__ __align__(16) unsigned short hY[DIM * NP];      // h^T then Y^T[2][128][64]
    __shared__ float mu_s[SEQ], rs_s[SEQ];
    __shared__ float mask_s[KP];

    const int b = blockIdx.x, t = threadIdx.x;
    const int lane = t & 63, wv = t >> 6;
    const int g4 = lane >> 4;

    // phase 0: fwd table + stats + mask
    {
        const int4* g = (const int4*)imgF;
        int4* lp = (int4*)tbl;
        #pragma unroll
        for (int j = 0; j < 8; ++j) lp[t + j * 256] = g[t + j * 256];
    }
    if (t < SEQ) {
        const float2 ms = *(const float2*)&mustat[((size_t)b * SEQ + t) * 2];
        mu_s[t] = ms.x; rs_s[t] = ms.y;
    }
    if (t >= 128 && t < 128 + KP) {
        const int k = t - 128;
        mask_s[k] = (k < NF && normE[b * NF + k] < thresh[0]) ? 1.f : 0.f;
    }
    __syncthreads();

    // phase 1: h^T build
    {
        const int c = t & 127, g2 = t >> 7;
        const float ga = gamma[c], be = beta[c];
        for (int ch = g2; ch < 16; ch += 2) {
            bf16x8 v;
            #pragma unroll
            for (int j = 0; j < 8; ++j) {
                const int n = ch * 8 + j;
                float hv = 0.f;
                if (n < SEQ)
                    hv = fmaf((x[(size_t)n * BD + (size_t)b * DIM + c] - mu_s[n]) * rs_s[n], ga, be);
                v[j] = (short)f2bf(hv);
            }
            *(bf16x8*)&hY[c * NP + ((ch ^ (c & 7)) << 3)] = v;
        }
    }
    __syncthreads();

    // phase 2: fwd MFMA
    f32x4v aR[8], aI[8];
    #pragma unroll
    for (int i = 0; i < 8; ++i) { aR[i] = (f32x4v){0.f,0.f,0.f,0.f}; aI[i] = (f32x4v){0.f,0.f,0.f,0.f}; }
    {
        const int r = wv * 16 + (lane & 15);
        bf16x8 A0[4], A1[4];
        #pragma unroll
        for (int ks = 0; ks < 4; ++ks) {
            const int ch = ks * 4 + g4;
            const int swz = (ch ^ (r & 7)) << 3;
            A0[ks] = *(const bf16x8*)&tbl[r * NP + swz];
            A1[ks] = *(const bf16x8*)&tbl[(KP + r) * NP + swz];
        }
        #pragma unroll
        for (int ks = 0; ks < 4; ++ks) {
            const int ch = ks * 4 + g4;
            #pragma unroll
            for (int nt = 0; nt < 8; ++nt) {
                const int c = nt * 16 + (lane & 15);
                const bf16x8 B = *(const bf16x8*)&hY[c * NP + ((ch ^ (c & 7)) << 3)];
                aR[nt] = __builtin_amdgcn_mfma_f32_16x16x32_bf16(A0[ks], B, aR[nt], 0, 0, 0);
                aI[nt] = __builtin_amdgcn_mfma_f32_16x16x32_bf16(A1[ks], B, aI[nt], 0, 0, 0);
            }
        }
    }

    // phase 3: Y = X * (w + mask*wh)   (in-register complex multiply)
    #pragma unroll
    for (int nt = 0; nt < 8; ++nt) {
        const int c = nt * 16 + (lane & 15);
        const float2 w2 = *(const float2*)&cw[2 * c];
        const float2 h2 = *(const float2*)&cwh[2 * c];
        #pragma unroll
        for (int reg = 0; reg < 4; ++reg) {
            const int k = wv * 16 + g4 * 4 + reg;
            const float m = mask_s[k];
            const float fre = fmaf(m, h2.x, w2.x);
            const float fim = fmaf(m, h2.y, w2.y);
            const float xr = aR[nt][reg], xi = aI[nt][reg];
            aR[nt][reg] = xr * fre - xi * fim;
            aI[nt][reg] = xr * fim + xi * fre;
        }
    }
    __syncthreads();   // all fwd reads of tbl/hY complete

    // phase 4: write Y^T (bf16, swizzled) + stage inverse table
    {
        const int k0 = wv * 16 + g4 * 4;
        #pragma unroll
        for (int nt = 0; nt < 8; ++nt) {
            const int c = nt * 16 + (lane & 15);
            bf16x4 vr, vi;
            #pragma unroll
            for (int reg = 0; reg < 4; ++reg) {
                vr[reg] = (short)f2bf(aR[nt][reg]);
                vi[reg] = (short)f2bf(aI[nt][reg]);
            }
            const int swz = ((((k0 >> 3) ^ (c & 7)) << 3) | (k0 & 7));
            *(bf16x4*)&hY[c * KP + swz] = vr;
            *(bf16x4*)&hY[8192 + c * KP + swz] = vi;
        }
        const int4* g = (const int4*)imgI;
        int4* lp = (int4*)tbl;
        #pragma unroll
        for (int j = 0; j < 8; ++j) lp[t + j * 256] = g[t + j * 256];
    }
    __syncthreads();

    // phase 5: inverse MFMA. wave wv owns n rows 32wv..32wv+31 (2 m-tiles)
    f32x4v o[2][8];
    #pragma unroll
    for (int mt = 0; mt < 2; ++mt)
        #pragma unroll
        for (int nt = 0; nt < 8; ++nt) o[mt][nt] = (f32x4v){0.f,0.f,0.f,0.f};

    bf16x8 IA[2][2][2];   // [p][mt][ks]
    #pragma unroll
    for (int mt = 0; mt < 2; ++mt)
        #pragma unroll
        for (int ks = 0; ks < 2; ++ks) {
            const int rr = wv * 32 + mt * 16 + (lane & 15);
            const int ch = ks * 4 + g4;
            const int swz = (ch ^ (rr & 7)) << 3;
            IA[0][mt][ks] = *(const bf16x8*)&tbl[rr * KP + swz];
            IA[1][mt][ks] = *(const bf16x8*)&tbl[8192 + rr * KP + swz];
        }
    #pragma unroll
    for (int ks = 0; ks < 2; ++ks) {
        #pragma unroll
        for (int nt = 0; nt < 8; ++nt) {
            const int c = nt * 16 + (lane & 15);
            const int ch = ks * 4 + g4;
            const int swz = (ch ^ (c & 7)) << 3;
            const bf16x8 Br = *(const bf16x8*)&hY[c * KP + swz];
            const bf16x8 Bi = *(const bf16x8*)&hY[8192 + c * KP + swz];
            #pragma unroll
            for (int mt = 0; mt < 2; ++mt) {
                o[mt][nt] = __builtin_amdgcn_mfma_f32_16x16x32_bf16(IA[0][mt][ks], Br, o[mt][nt], 0, 0, 0);
                o[mt][nt] = __builtin_amdgcn_mfma_f32_16x16x32_bf16(IA[1][mt][ks], Bi, o[mt][nt], 0, 0, 0);
            }
        }
    }

    // phase 6: residual + store (skip padded n >= 100)
    #pragma unroll
    for (int mt = 0; mt < 2; ++mt)
        #pragma unroll
        for (int nt = 0; nt < 8; ++nt)
            #pragma unroll
            for (int reg = 0; reg < 4; ++reg) {
                const int n = wv * 32 + mt * 16 + g4 * 4 + reg;
                if (n < SEQ) {
                    const int c = nt * 16 + (lane & 15);
                    const size_t idx = (size_t)n * BD + (size_t)b * DIM + c;
                    out[idx] = x[idx] + o[mt][nt][reg];
                }
            }
}

// ---------------------------------------------------------------------------
extern "C" void kernel_launch(void* const* d_in, const int* in_sizes, int n_in,
                              void* d_out, int out_size, void* d_ws, size_t ws_size,
                              hipStream_t stream)
{
    const float* x    = (const float*)d_in[0];
    const float* cw   = (const float*)d_in[1];
    const float* cwh  = (const float*)d_in[2];
    const float* thrp = (const float*)d_in[3];
    const float* gam  = (const float*)d_in[4];
    const float* bet  = (const float*)d_in[5];
    float* out = (float*)d_out;

    char* ws = (char*)d_ws;
    size_t off = 0;
    unsigned short* imgF = (unsigned short*)(ws + off); off += 32768;
    unsigned short* imgI = (unsigned short*)(ws + off); off += 32768;
    float* normE  = (float*)(ws + off); off += (size_t)MTOT * 4;        // 417792
    off = (off + 255) & ~(size_t)255;
    float* mustat = (float*)(ws + off); off += (size_t)BATCH * SEQ * 8; // 1.64 MB
    off = (off + 255) & ~(size_t)255;
    unsigned* hist = (unsigned*)(ws + off); off += 4096 * 4;
    unsigned* sel  = (unsigned*)(ws + off); off += 64;
    float* thresh  = (float*)(ws + off);

    k_tables<<<64, 256, 0, stream>>>(imgF, imgI);
    hipMemsetAsync(hist, 0, 4096 * sizeof(unsigned), stream);

    for (int l = 0; l < NLAYER; ++l) {
        const float* xi = (l == 0) ? x : out;
        k_fwd<<<BATCH, 256, 0, stream>>>(xi, gam + l * DIM, bet + l * DIM,
                                         imgF, mustat, normE);
        for (int r = 0; r < 3; ++r) {
            k_hist<<<96, 256, 0, stream>>>(normE, hist, sel, r);
            k_scan<<<1, 128, 0, stream>>>(hist, sel, thrp, l, r, thresh);
        }
        k_asb<<<BATCH, 256, 0, stream>>>(xi, gam + l * DIM, bet + l * DIM,
                                         cw + l * DIM * 2, cwh + l * DIM * 2,
                                         imgF, imgI, mustat, normE, thresh, out);
    }
}

// Round 3
// 416.705 us; speedup vs baseline: 1.5759x; 1.5024x over previous
//
#include <hip/hip_runtime.h>
#include <math.h>

#define SEQ    100
#define BATCH  2048
#define DIM    128
#define NF     51
#define NLAYER 2
#define MTOT   (BATCH * NF)
#define BD     (BATCH * DIM)

typedef __attribute__((ext_vector_type(8))) short bf16x8;
typedef __attribute__((ext_vector_type(4))) short bf16x4;
typedef __attribute__((ext_vector_type(4))) float f32x4v;

__device__ __forceinline__ unsigned short f2bf(float f) {
    unsigned u = __float_as_uint(f);
    return (unsigned short)((u + 0x7FFFu + ((u >> 16) & 1u)) >> 16);
}

// ---------------------------------------------------------------- tables ---
// imgF [p][k][n] bf16: p0 = 0.1*cos(2pi k n/100), p1 = -0.1*sin; zero pad.
// imgI [p][n][k] bf16: p0 = a_k*cos,  p1 = -a_k*sin; a_k = 0.1 or 0.2.
__global__ void k_tables(unsigned short* __restrict__ imgF,
                         unsigned short* __restrict__ imgI) {
    const int i = blockIdx.x * 256 + threadIdx.x;   // 16384 per table
    const float W = 6.28318530717958647692f / 100.f;
    if (i < 2 * 64 * 128) {
        const int p = i >> 13, k = (i >> 7) & 63, n = i & 127;
        float v = 0.f;
        if (k < NF && n < SEQ) {
            float s, c; sincosf((float)((k * n) % 100) * W, &s, &c);
            v = 0.1f * (p ? -s : c);
        }
        imgF[i] = f2bf(v);
    }
    if (i < 2 * 128 * 64) {
        const int p = i >> 13, n = (i >> 6) & 127, k = i & 63;
        float v = 0.f;
        if (k < NF && n < SEQ) {
            float s, c; sincosf((float)((k * n) % 100) * W, &s, &c);
            const float a = (k == 0 || k == 50) ? 0.1f : 0.2f;
            v = p ? -a * s : a * c;
        }
        imgI[i] = f2bf(v);
    }
}

// ------------------------------------------ LN + h^T staging (one x pass) --
// h^T LDS image: element (c, n) at ushort index c*128 + ((n>>3)^(c&7))*8 + (n&7)
// (XOR-swizzled 16B chunks; b128 fragment reads hit the throughput floor).
__device__ __forceinline__ void ln_stage(const float* __restrict__ x,
                                         const float* __restrict__ gamma,
                                         const float* __restrict__ beta,
                                         unsigned short* hT, int b, int t)
{
    const int lane = t & 63, wv = t >> 6;
    const int half = lane >> 5, li = lane & 31;
    const int c0 = li * 4;

    // zero n>=100 padding (A-table is zero there too, but LDS garbage may be NaN)
    for (int i = t; i < 128 * 3; i += 256) {
        const int c = i / 3, ch = 13 + (i - (i / 3) * 3);
        *(int4*)&hT[c * 128 + ((ch ^ (c & 7)) << 3)] = (int4){0, 0, 0, 0};
    }
    if (t < 128) {
        const int c = t;
        *(int2*)&hT[c * 128 + ((12 ^ (c & 7)) << 3) + 4] = (int2){0, 0};
    }

    const float4 gv = *(const float4*)&gamma[c0];
    const float4 bv = *(const float4*)&beta[c0];

    // wave wv owns rows [25*wv, 25*wv+25); half-waves process 2 rows at a time
    #pragma unroll
    for (int i = 0; i < 13; ++i) {
        const int r = 2 * i + half;
        if (r < 25) {
            const int n = wv * 25 + r;
            const float4 v = *(const float4*)&x[(size_t)n * BD + (size_t)b * DIM + c0];
            float s  = (v.x + v.y) + (v.z + v.w);
            float s2 = fmaf(v.x, v.x, fmaf(v.y, v.y, fmaf(v.z, v.z, v.w * v.w)));
            #pragma unroll
            for (int off = 1; off < 32; off <<= 1) {
                s  += __shfl_xor(s,  off, 64);
                s2 += __shfl_xor(s2, off, 64);
            }
            const float mu   = s * (1.f / 128.f);
            const float rstd = rsqrtf(s2 * (1.f / 128.f) - mu * mu + 1e-5f);
            float hv[4];
            hv[0] = fmaf((v.x - mu) * rstd, gv.x, bv.x);
            hv[1] = fmaf((v.y - mu) * rstd, gv.y, bv.y);
            hv[2] = fmaf((v.z - mu) * rstd, gv.z, bv.z);
            hv[3] = fmaf((v.w - mu) * rstd, gv.w, bv.w);
            #pragma unroll
            for (int w = 0; w < 4; ++w) {
                const int c = c0 + w;
                hT[c * 128 + ((((n >> 3) ^ (c & 7)) << 3)) + (n & 7)] = f2bf(hv[w]);
            }
        }
    }
}

// ------------------------------------------------- A: LN + fwd DFT + normE -
__global__ __launch_bounds__(256, 4) void k_fwd(
    const float* __restrict__ x,
    const float* __restrict__ gamma, const float* __restrict__ beta,
    const unsigned short* __restrict__ imgF,
    float* __restrict__ normE)
{
    __shared__ __align__(16) unsigned short hT[128 * 128];   // 32 KB
    __shared__ float epart[64][4];
    __shared__ float energy_s[64];
    __shared__ float med_s;

    const int b = blockIdx.x, t = threadIdx.x;
    const int lane = t & 63, wv = t >> 6, g4 = lane >> 4, cc = lane & 15;

    ln_stage(x, gamma, beta, hT, b, t);
    __syncthreads();

    // fwd B-fragments for this wave's 2 c-tiles (held in registers)
    bf16x8 Bf[2][4];
    #pragma unroll
    for (int ct = 0; ct < 2; ++ct) {
        const int c = wv * 32 + ct * 16 + cc;
        #pragma unroll
        for (int ks = 0; ks < 4; ++ks)
            Bf[ct][ks] = *(const bf16x8*)&hT[c * 128 + (((ks * 4 + g4) ^ (c & 7)) << 3)];
    }

    #pragma unroll
    for (int mt = 0; mt < 4; ++mt) {
        const int kr = mt * 16 + cc;
        f32x4v aR[2], aI[2];
        aR[0] = aR[1] = aI[0] = aI[1] = (f32x4v){0.f, 0.f, 0.f, 0.f};
        #pragma unroll
        for (int ks = 0; ks < 4; ++ks) {
            const int e0 = kr * 128 + ks * 32 + g4 * 8;
            const bf16x8 A0 = *(const bf16x8*)&imgF[e0];
            const bf16x8 A1 = *(const bf16x8*)&imgF[8192 + e0];
            #pragma unroll
            for (int ct = 0; ct < 2; ++ct) {
                aR[ct] = __builtin_amdgcn_mfma_f32_16x16x32_bf16(A0, Bf[ct][ks], aR[ct], 0, 0, 0);
                aI[ct] = __builtin_amdgcn_mfma_f32_16x16x32_bf16(A1, Bf[ct][ks], aI[ct], 0, 0, 0);
            }
        }
        #pragma unroll
        for (int reg = 0; reg < 4; ++reg) {
            float e = aR[0][reg] * aR[0][reg] + aI[0][reg] * aI[0][reg]
                    + aR[1][reg] * aR[1][reg] + aI[1][reg] * aI[1][reg];
            e += __shfl_xor(e, 1, 64); e += __shfl_xor(e, 2, 64);
            e += __shfl_xor(e, 4, 64); e += __shfl_xor(e, 8, 64);
            if (cc == 0) epart[mt * 16 + g4 * 4 + reg][wv] = e;
        }
    }
    __syncthreads();
    if (t < 64) energy_s[t] = epart[t][0] + epart[t][1] + epart[t][2] + epart[t][3];
    __syncthreads();
    if (t < NF) {
        const float e = energy_s[t];
        int cnt = 0;
        for (int j = 0; j < NF; ++j) {
            const float ej = energy_s[j];
            cnt += (ej < e || (ej == e && j < t)) ? 1 : 0;
        }
        if (cnt == (NF - 1) / 2) med_s = e;
    }
    __syncthreads();
    if (t < NF) normE[b * NF + t] = energy_s[t] / (med_s + 1e-6f);
}

// --------------------------------------------- fused hist+scan per round ---
__global__ void k_quant(const float* __restrict__ normE,
                        unsigned* __restrict__ hist,
                        unsigned* __restrict__ sel,
                        unsigned* __restrict__ done,
                        const float* __restrict__ thrp,
                        const int layer, const int round,
                        float* __restrict__ thresh)
{
    __shared__ unsigned lh[4096];
    __shared__ unsigned ticket_s;
    __shared__ float vbits_s[2];
    const int bins  = (round == 2) ? 1024 : 2048;
    const int shift = (round == 0) ? 21 : (round == 1) ? 10 : 0;
    const int nh    = (round == 0) ? bins : 2 * bins;

    for (int i = threadIdx.x; i < nh; i += 256) lh[i] = 0;
    __syncthreads();
    unsigned p0 = 0, p1 = 0, himask = 0;
    if (round > 0) {
        p0 = sel[0]; p1 = sel[2];
        himask = (round == 1) ? 0xFFE00000u : 0xFFFFFC00u;
    }
    for (int i = blockIdx.x * 256 + threadIdx.x; i < MTOT; i += gridDim.x * 256) {
        const unsigned v = __float_as_uint(normE[i]);
        if (round == 0) {
            atomicAdd(&lh[v >> 21], 1u);
        } else {
            const unsigned bin = (v >> shift) & (unsigned)(bins - 1);
            if ((v & himask) == p0) atomicAdd(&lh[bin], 1u);
            if ((v & himask) == p1) atomicAdd(&lh[bins + bin], 1u);
        }
    }
    __syncthreads();
    for (int i = threadIdx.x; i < nh; i += 256) {
        const unsigned c = lh[i];
        if (c) atomicAdd(&hist[i], c);
    }
    __threadfence();
    if (threadIdx.x == 0) ticket_s = atomicAdd(done, 1u);
    __syncthreads();
    if (ticket_s != (unsigned)(gridDim.x - 1)) return;
    __threadfence();

    // last block: scan both ranks
    const float thr  = thrp[layer];
    const float qpos = thr * (float)(MTOT - 1);
    const float lo   = floorf(qpos);
    if (threadIdx.x < 128) {
        const int j = threadIdx.x >> 6, ln2 = threadIdx.x & 63;
        const unsigned r = (unsigned)lo + (unsigned)j;
        unsigned prefix = 0, cbelow = 0;
        if (round > 0) { prefix = sel[2 * j]; cbelow = sel[2 * j + 1]; }
        const unsigned rem = r - cbelow;
        const unsigned hb  = (round == 0) ? 0u : (unsigned)(j * bins);
        const int per = bins / 64;
        unsigned sum = 0;
        for (int i = 0; i < per; ++i)
            sum += __hip_atomic_load(&hist[hb + ln2 * per + i],
                                     __ATOMIC_RELAXED, __HIP_MEMORY_SCOPE_AGENT);
        unsigned pre = sum;
        #pragma unroll
        for (int off = 1; off < 64; off <<= 1) {
            const unsigned tt = __shfl_up(pre, off, 64);
            if (ln2 >= off) pre += tt;
        }
        const unsigned excl = pre - sum;
        if (rem >= excl && rem < excl + sum) {
            unsigned cum = excl, tb = 0;
            for (int i = 0; i < per; ++i) {
                const unsigned hc = __hip_atomic_load(&hist[hb + ln2 * per + i],
                                     __ATOMIC_RELAXED, __HIP_MEMORY_SCOPE_AGENT);
                if (rem < cum + hc) { tb = (unsigned)(ln2 * per + i); break; }
                cum += hc;
            }
            sel[2 * j]     = prefix | (tb << shift);
            sel[2 * j + 1] = cbelow + cum;
            if (round == 2) vbits_s[j] = __uint_as_float(prefix | tb);
        }
    }
    __syncthreads();
    for (int i = threadIdx.x; i < 4096; i += 256) hist[i] = 0u;
    if (threadIdx.x == 0) {
        *done = 0u;
        if (round == 2) {
            const float frac = qpos - lo;
            thresh[0] = vbits_s[0] * (1.f - frac) + vbits_s[1] * frac;
        }
    }
}

// --------------------- C: LN + fwd DFT + weight + inv DFT + residual -------
__global__ __launch_bounds__(256, 4) void k_asb(
    const float* __restrict__ x,
    const float* __restrict__ gamma, const float* __restrict__ beta,
    const float* __restrict__ cw, const float* __restrict__ cwh,
    const unsigned short* __restrict__ imgF,
    const unsigned short* __restrict__ imgI,
    const float* __restrict__ normE, const float* __restrict__ thresh,
    float* __restrict__ out)
{
    __shared__ __align__(16) unsigned short hT[128 * 128];   // h^T, then Y^T in-place
    __shared__ float mask_s[64];

    const int b = blockIdx.x, t = threadIdx.x;
    const int lane = t & 63, wv = t >> 6, g4 = lane >> 4, cc = lane & 15;

    if (t < 64) mask_s[t] = (t < NF && normE[b * NF + t] < thresh[0]) ? 1.f : 0.f;
    ln_stage(x, gamma, beta, hT, b, t);
    __syncthreads();   // the only block-wide barrier

    // fwd B-fragments (registers) — after this, this wave's rows are reusable
    bf16x8 Bf[2][4];
    #pragma unroll
    for (int ct = 0; ct < 2; ++ct) {
        const int c = wv * 32 + ct * 16 + cc;
        #pragma unroll
        for (int ks = 0; ks < 4; ++ks)
            Bf[ct][ks] = *(const bf16x8*)&hT[c * 128 + (((ks * 4 + g4) ^ (c & 7)) << 3)];
    }

    // complex weights per owned channel
    float fwr[2], fwi[2], fhr[2], fhi[2];
    #pragma unroll
    for (int ct = 0; ct < 2; ++ct) {
        const int c = wv * 32 + ct * 16 + cc;
        const float2 w2 = *(const float2*)&cw[2 * c];
        const float2 h2 = *(const float2*)&cwh[2 * c];
        fwr[ct] = w2.x; fwi[ct] = w2.y; fhr[ct] = h2.x; fhi[ct] = h2.y;
    }

    // fwd DFT + weighting; Y^T overwrites this wave's own h^T rows:
    // Y(plane,c,k) at ushort index c*128 + plane*64 + ((k>>3)^(c&7))*8 + (k&7)
    #pragma unroll
    for (int mt = 0; mt < 4; ++mt) {
        const int kr = mt * 16 + cc;
        f32x4v aR[2], aI[2];
        aR[0] = aR[1] = aI[0] = aI[1] = (f32x4v){0.f, 0.f, 0.f, 0.f};
        #pragma unroll
        for (int ks = 0; ks < 4; ++ks) {
            const int e0 = kr * 128 + ks * 32 + g4 * 8;
            const bf16x8 A0 = *(const bf16x8*)&imgF[e0];
            const bf16x8 A1 = *(const bf16x8*)&imgF[8192 + e0];
            #pragma unroll
            for (int ct = 0; ct < 2; ++ct) {
                aR[ct] = __builtin_amdgcn_mfma_f32_16x16x32_bf16(A0, Bf[ct][ks], aR[ct], 0, 0, 0);
                aI[ct] = __builtin_amdgcn_mfma_f32_16x16x32_bf16(A1, Bf[ct][ks], aI[ct], 0, 0, 0);
            }
        }
        #pragma unroll
        for (int ct = 0; ct < 2; ++ct) {
            const int c = wv * 32 + ct * 16 + cc;
            bf16x4 vr, vi;
            #pragma unroll
            for (int reg = 0; reg < 4; ++reg) {
                const float m   = mask_s[mt * 16 + g4 * 4 + reg];
                const float fre = fmaf(m, fhr[ct], fwr[ct]);
                const float fim = fmaf(m, fhi[ct], fwi[ct]);
                const float xr = aR[ct][reg], xi = aI[ct][reg];
                vr[reg] = (short)f2bf(xr * fre - xi * fim);
                vi[reg] = (short)f2bf(xr * fim + xi * fre);
            }
            const int chY = mt * 2 + (g4 >> 1);
            const int eb  = c * 128 + ((chY ^ (c & 7)) << 3) + (g4 & 1) * 4;
            *(bf16x4*)&hT[eb]      = vr;   // plane 0 (Re)
            *(bf16x4*)&hT[eb + 64] = vi;   // plane 1 (Im)
        }
    }

    // inverse B-fragments from own Y rows
    bf16x8 Yr[2][2], Yi[2][2];
    #pragma unroll
    for (int ct = 0; ct < 2; ++ct) {
        const int c = wv * 32 + ct * 16 + cc;
        #pragma unroll
        for (int kb = 0; kb < 2; ++kb) {
            const int sw = (((kb * 4 + g4) ^ (c & 7)) << 3);
            Yr[ct][kb] = *(const bf16x8*)&hT[c * 128 + sw];
            Yi[ct][kb] = *(const bf16x8*)&hT[c * 128 + 64 + sw];
        }
    }

    // inverse DFT + residual + store
    #pragma unroll
    for (int mt = 0; mt < 7; ++mt) {
        const int nr = mt * 16 + cc;
        f32x4v o[2];
        o[0] = o[1] = (f32x4v){0.f, 0.f, 0.f, 0.f};
        #pragma unroll
        for (int kb = 0; kb < 2; ++kb) {
            const int e0 = nr * 64 + kb * 32 + g4 * 8;
            const bf16x8 A0 = *(const bf16x8*)&imgI[e0];
            const bf16x8 A1 = *(const bf16x8*)&imgI[8192 + e0];
            #pragma unroll
            for (int ct = 0; ct < 2; ++ct) {
                o[ct] = __builtin_amdgcn_mfma_f32_16x16x32_bf16(A0, Yr[ct][kb], o[ct], 0, 0, 0);
                o[ct] = __builtin_amdgcn_mfma_f32_16x16x32_bf16(A1, Yi[ct][kb], o[ct], 0, 0, 0);
            }
        }
        #pragma unroll
        for (int ct = 0; ct < 2; ++ct) {
            const int c = wv * 32 + ct * 16 + cc;
            #pragma unroll
            for (int reg = 0; reg < 4; ++reg) {
                const int n = mt * 16 + g4 * 4 + reg;
                if (n < SEQ) {
                    const size_t idx = (size_t)n * BD + (size_t)b * DIM + c;
                    out[idx] = x[idx] + o[ct][reg];
                }
            }
        }
    }
}

// ---------------------------------------------------------------------------
extern "C" void kernel_launch(void* const* d_in, const int* in_sizes, int n_in,
                              void* d_out, int out_size, void* d_ws, size_t ws_size,
                              hipStream_t stream)
{
    (void)in_sizes; (void)n_in; (void)out_size; (void)ws_size;
    const float* x    = (const float*)d_in[0];
    const float* cw   = (const float*)d_in[1];
    const float* cwh  = (const float*)d_in[2];
    const float* thrp = (const float*)d_in[3];
    const float* gam  = (const float*)d_in[4];
    const float* bet  = (const float*)d_in[5];
    float* out = (float*)d_out;

    char* ws = (char*)d_ws;
    unsigned short* imgF = (unsigned short*)(ws);            // 32768 B
    unsigned short* imgI = (unsigned short*)(ws + 32768);    // 32768 B
    float* normE   = (float*)(ws + 65536);                   // 417792 B
    unsigned* hist = (unsigned*)(ws + 483328);               // 16384 B
    unsigned* sel  = (unsigned*)(ws + 499712);               // 64 B
    unsigned* done = (unsigned*)(ws + 499776);               // 64 B
    float* thresh  = (float*)(ws + 499840);

    k_tables<<<64, 256, 0, stream>>>(imgF, imgI);
    hipMemsetAsync(hist, 0, 16384 + 64 + 64, stream);        // hist + sel + done

    for (int l = 0; l < NLAYER; ++l) {
        const float* xi = (l == 0) ? x : out;
        k_fwd<<<BATCH, 256, 0, stream>>>(xi, gam + l * DIM, bet + l * DIM, imgF, normE);
        for (int r = 0; r < 3; ++r)
            k_quant<<<96, 256, 0, stream>>>(normE, hist, sel, done, thrp, l, r, thresh);
        k_asb<<<BATCH, 256, 0, stream>>>(xi, gam + l * DIM, bet + l * DIM,
                                         cw + l * DIM * 2, cwh + l * DIM * 2,
                                         imgF, imgI, normE, thresh, out);
    }
}